// Round 8
// baseline (1054.613 us; speedup 1.0000x reference)
//
#include <hip/hip_runtime.h>

typedef unsigned short u16;
typedef short s16x8 __attribute__((ext_vector_type(8)));
typedef float f32x4 __attribute__((ext_vector_type(4)));

#define LAYERS   64
#define M_NODES  2048
#define DIM      128
#define FD       512
#define CHUNK    16
#define NBLK     128     // M_NODES / CHUNK
#define TPB      512     // 8 waves; wave wv owns hidden dims [wv*16, wv*16+16)
#define XPAD     136     // 128 + 8 pad u16 (16B-aligned rows)

__device__ __forceinline__ u16 f2bf(float f) {
    union { float f; unsigned int i; } v; v.f = f;
    unsigned int r = (v.i + 0x7FFFu + ((v.i >> 16) & 1u)) >> 16;
    return (u16)r;
}
__device__ __forceinline__ float bf2f(u16 h) {
    union { unsigned int i; float f; } v; v.i = ((unsigned int)h) << 16;
    return v.f;
}
__device__ __forceinline__ float sigm(float x) {
    return __builtin_amdgcn_rcpf(1.0f + __builtin_exp2f(-1.44269504f * x));
}
__device__ __forceinline__ float tanh_f(float x) {
    float ax = __builtin_fabsf(x);
    float t  = __builtin_exp2f(-2.88539008f * ax);   // exp(-2|x|)
    float r  = (1.0f - t) * __builtin_amdgcn_rcpf(1.0f + t);
    return __builtin_copysignf(r, x);
}

// ---------------- standalone layer 0 (fallback path only) ----------------
__global__ void l0_kernel(const int* __restrict__ names, const float* __restrict__ table,
                          float* __restrict__ emb) {
    int v = blockIdx.x * blockDim.x + threadIdx.x;      // 2048 rows * 32 float4
    if (v >= M_NODES * (DIM / 4)) return;
    int row = v >> 5, c = v & 31;
    const float4* src = (const float4*)(table + (size_t)names[row] * DIM);
    ((float4*)(emb + (size_t)row * DIM))[c] = src[c];
}

// =============== merged setup: repack (blocks 0-127) + t0 hoist (block 128) + l0 (129-384) ===============
// packed[(((mat*4+kc)*32+ntile)*64+lane)*8+j] = bf16(B[kc*32+(lane>>4)*8+j][ntile*16+(lane&15)])
// t0buf: [0..127] = c1; [128 + g*128 + d] = uh1[g][d]   (layer-invariant LSTM_m t=0)
// l0: emb[m] = table[names[m]] (fp32) and, if MIRROR, emb16[m] = bf16 of the same.
template <bool MIRROR>
__global__ void setup_kernel(const int* __restrict__ names, const float* __restrict__ table,
                             float* __restrict__ emb,
                             const float* __restrict__ Wm, const float* __restrict__ Um,
                             const float* __restrict__ Ws, const float* __restrict__ Us,
                             const float* __restrict__ bm, const float* __restrict__ empty,
                             u16* __restrict__ packed, float* __restrict__ t0buf,
                             u16* __restrict__ emb16) {
    const int blk = blockIdx.x;
    const int tid = threadIdx.x;
    if (blk < 128) {                                    // ---- repack ----
        int t = blk * 256 + tid;                        // 32768 threads
        int lane = t & 63, ntg = (t >> 6) & 31, kc = (t >> 11) & 3, mat = t >> 13;
        const float* B = (mat == 0) ? Wm : (mat == 1) ? Um : (mat == 2) ? Ws : Us;
        int q = lane >> 4, nl = lane & 15;
        int kb = kc * 32 + q * 8;
        int n  = ntg * 16 + nl;
        u16* dst = packed + ((((size_t)mat * 4 + kc) * 32 + ntg) * 64 + lane) * 8;
        #pragma unroll
        for (int j = 0; j < 8; j++) dst[j] = f2bf(B[(size_t)(kb + j) * FD + n]);
    } else if (blk == 128) {                            // ---- t0 hoist ----
        __shared__ float h1s[DIM];
        int dd = tid;
        if (dd < DIM) {
            float z0 = bm[dd], z1 = bm[256 + dd], z2 = bm[384 + dd];
            for (int k = 0; k < DIM; k++) {
                float e = empty[k];
                const float* Wr = Wm + (size_t)k * FD;
                z0 += e * Wr[dd];                       // i gate
                z1 += e * Wr[256 + dd];                 // g gate
                z2 += e * Wr[384 + dd];                 // o gate (f irrelevant: c_prev=0)
            }
            float c1 = sigm(z0) * tanh_f(z1);
            float h1 = sigm(z2) * tanh_f(c1);
            t0buf[dd] = c1;
            h1s[dd] = h1;
        }
        __syncthreads();
        if (dd < DIM) {
            float u0 = 0.f, u1 = 0.f, u2 = 0.f, u3 = 0.f;
            for (int k = 0; k < DIM; k++) {
                float hb = bf2f(f2bf(h1s[k]));          // same bf16 rounding as the MFMA path
                const float* Ur = Um + (size_t)k * FD;
                u0 += hb * bf2f(f2bf(Ur[dd]));
                u1 += hb * bf2f(f2bf(Ur[128 + dd]));
                u2 += hb * bf2f(f2bf(Ur[256 + dd]));
                u3 += hb * bf2f(f2bf(Ur[384 + dd]));
            }
            t0buf[128 + 0 * 128 + dd] = u0;
            t0buf[128 + 1 * 128 + dd] = u1;
            t0buf[128 + 2 * 128 + dd] = u2;
            t0buf[128 + 3 * 128 + dd] = u3;
        }
    } else {                                            // ---- l0 ----
        int v = (blk - 129) * 256 + tid;                // 65536 float4s
        if (v >= M_NODES * (DIM / 4)) return;
        int row = v >> 5, c = v & 31;
        const float4* src = (const float4*)(table + (size_t)names[row] * DIM);
        float4 vv = src[c];
        ((float4*)(emb + (size_t)row * DIM))[c] = vv;
        if (MIRROR) {
            ushort4 w;
            w.x = f2bf(vv.x); w.y = f2bf(vv.y); w.z = f2bf(vv.z); w.w = f2bf(vv.w);
            *(ushort4*)(emb16 + (size_t)row * DIM + c * 4) = w;
        }
    }
}

// ======================= per-layer kernel, merged 5-step schedule =======================
// Coherence via dispatch boundaries (proven cheapest across r1-r5). MIRROR: gather reads the
// bf16 emb16 mirror; step5 writes both fp32 emb and emb16.
// r8: weight-stream software pipelining — every 16KB/wave L2 fragment stream is issued >=1
// phase before its first consumer so L2 latency hides under compute:
//   pre-S0: wfs + wfm (hide under gather idx->row chain)
//   post-Zx-s: ufm (hides under Zx-m's 64 MFMAs)
//   post-S1:  ufs (hides under step2)
//   top of step4: wfs2 (hides under step4's MFMAs, consumed in step5)
template <bool MIRROR>
__global__ __launch_bounds__(TPB, 1) void layer5_kernel(
    float* __restrict__ emb, const int* __restrict__ prop_ids, const int* __restrict__ super_ids,
    const float* __restrict__ bm, const float* __restrict__ bs,
    const u16* __restrict__ packed, const float* __restrict__ t0buf,
    u16* __restrict__ emb16, int l) {

    // slots 0..3: prop embeddings (slot 0 reused for h_m); slots 4..5: super embeddings
    __shared__ __align__(16) u16 xs[6][CHUNK][XPAD];
    __shared__ __align__(16) u16 hbM[2][CHUNK][XPAD];
    __shared__ __align__(16) u16 hbS[2][CHUNK][XPAD];

    const int tid  = threadIdx.x;
    const int b    = blockIdx.x;
    const int g0   = b * CHUNK;
    const int wv   = tid >> 6;          // 0..7
    const int lane = tid & 63;
    const int q    = lane >> 4, nl = lane & 15;
    const int d    = wv * 16 + nl;      // this lane's hidden dim

    auto ldB = [&](int mat, int kc, int g) -> s16x8 {
        return *(const s16x8*)(packed + ((((size_t)mat * 4 + kc) * 32 + (g * 8 + wv)) * 64 + lane) * 8);
    };
    auto load_afrag = [&](const u16* X /* [CHUNK][XPAD] base */, int kc) -> s16x8 {
        return *(const s16x8*)(X + (size_t)nl * XPAD + kc * 32 + q * 8);
    };

    // ---- gather: 96 rows -> bf16 LDS tiles (waves 0-5) ----
    if (tid < 384) {
        int quarter = tid & 3;
        int r    = tid >> 2;
        int slot = r >> 4;
        int node = r & 15;
        size_t idx;
        if (slot < 4) idx = (size_t)prop_ids [((size_t)l * M_NODES + g0 + node) * 4 + slot];
        else          idx = (size_t)super_ids[((size_t)l * M_NODES + g0 + node) * 2 + (slot - 4)];
        if (MIRROR) {
            // bf16 row: 64B per lane, straight copy (no conversion)
            const s16x8* src = (const s16x8*)(emb16 + idx * DIM) + quarter * 4;
            u16* dst = &xs[slot][node][quarter * 32];
            #pragma unroll
            for (int j = 0; j < 4; j++) *(s16x8*)(dst + j * 8) = src[j];
        } else {
            const f32x4* src = (const f32x4*)(emb + idx * DIM) + quarter * 8;
            u16* dst = &xs[slot][node][0];
            int e0 = quarter * 32;
            #pragma unroll
            for (int j = 0; j < 8; j++) {
                f32x4 v = src[j];
                ushort4 w;
                w.x = f2bf(v[0]); w.y = f2bf(v[1]); w.z = f2bf(v[2]); w.w = f2bf(v[3]);
                *(ushort4*)(dst + e0 + j * 4) = w;
            }
        }
    }

    // ---- per-thread constants (all waves, overlaps gather) ----
    float bzm[4], bzs[4], uh1[4];
    #pragma unroll
    for (int g = 0; g < 4; g++) {
        bzm[g] = bm[g * 128 + d];
        bzs[g] = bs[g * 128 + d];
        uh1[g] = t0buf[128 + g * 128 + d];
    }
    const float c1 = t0buf[d];

    // ---- pre-S0 weight prefetch: Ws (Zx-s) AND Wm (Zx-m) — latency hides under gather ----
    s16x8 wfs[4][4], wfm[4][4];
    #pragma unroll
    for (int kc = 0; kc < 4; kc++)
        #pragma unroll
        for (int g = 0; g < 4; g++) {
            wfs[kc][g] = ldB(2, kc, g);
            wfm[kc][g] = ldB(0, kc, g);
        }

    __syncthreads();                                   // S0: gather visible

    // gates + store; mode 0: hbM[parity], 3: hbS[parity], 1: xs[0] (h_m), 2: emb (+mirror)
    auto gates = [&](const f32x4* acc, const float* bz, float* cc, int mode, int parity) {
        #pragma unroll
        for (int r2 = 0; r2 < 4; r2++) {
            int m = q * 4 + r2;
            float zi = acc[0][r2] + bz[0];
            float zf = acc[1][r2] + bz[1];
            float zg = acc[2][r2] + bz[2];
            float zo = acc[3][r2] + bz[3];
            float c  = sigm(zf) * cc[r2] + sigm(zi) * tanh_f(zg);
            cc[r2] = c;
            float h  = sigm(zo) * tanh_f(c);
            if (mode == 0)      hbM[parity][m][d] = f2bf(h);
            else if (mode == 3) hbS[parity][m][d] = f2bf(h);
            else if (mode == 1) xs[0][m][d] = f2bf(h);
            else {
                emb[((size_t)l * M_NODES + g0 + m) * DIM + d] = h;
                if (MIRROR) emb16[((size_t)l * M_NODES + g0 + m) * DIM + d] = f2bf(h);
            }
        }
    };

    // ---- Zx: zxs0, zxs1 = sup@Ws (wfs dies here) ----
    f32x4 zxs0[4], zxs1[4];
    #pragma unroll
    for (int g = 0; g < 4; g++) { zxs0[g] = (f32x4){0.f,0.f,0.f,0.f}; zxs1[g] = (f32x4){0.f,0.f,0.f,0.f}; }
    #pragma unroll
    for (int kc = 0; kc < 4; kc++) {
        s16x8 a4 = load_afrag(&xs[4][0][0], kc);
        s16x8 a5 = load_afrag(&xs[5][0][0], kc);
        #pragma unroll
        for (int g = 0; g < 4; g++) {
            zxs0[g] = __builtin_amdgcn_mfma_f32_16x16x32_bf16(a4, wfs[kc][g], zxs0[g], 0, 0, 0);
            zxs1[g] = __builtin_amdgcn_mfma_f32_16x16x32_bf16(a5, wfs[kc][g], zxs1[g], 0, 0, 0);
        }
    }

    // ---- issue ufm stream now: latency hides under Zx-m's 64 MFMAs ----
    s16x8 ufm[4][4];
    #pragma unroll
    for (int kc = 0; kc < 4; kc++)
        #pragma unroll
        for (int g = 0; g < 4; g++) ufm[kc][g] = ldB(1, kc, g);

    // ---- Zx: zxm[0..3] = prop@Wm (wfm dies here) ----
    f32x4 zxm[4][4];
    #pragma unroll
    for (int s = 0; s < 4; s++) {
        #pragma unroll
        for (int g = 0; g < 4; g++) zxm[s][g] = (f32x4){0.f, 0.f, 0.f, 0.f};
        #pragma unroll
        for (int kc = 0; kc < 4; kc++) {
            s16x8 a = load_afrag(&xs[s][0][0], kc);
            #pragma unroll
            for (int g = 0; g < 4; g++)
                zxm[s][g] = __builtin_amdgcn_mfma_f32_16x16x32_bf16(a, wfm[kc][g], zxm[s][g], 0, 0, 0);
        }
    }

    float ccm[4] = {c1, c1, c1, c1};
    float ccs[4] = {0.f, 0.f, 0.f, 0.f};

    {   // step1 (register-only): m-t1 = zxm[0]+uh1  ||  s-t0 = zxs0
        f32x4 accM[4];
        #pragma unroll
        for (int g = 0; g < 4; g++) accM[g] = zxm[0][g] + uh1[g];
        gates(accM, bzm, ccm, 0, 1);                   // write hbM[1]
        gates(zxs0, bzs, ccs, 3, 0);                   // write hbS[0]
    }
    __syncthreads();                                   // S1

    // ---- issue ufs stream now: latency hides under step2 ----
    s16x8 ufs[4][4];
    #pragma unroll
    for (int kc = 0; kc < 4; kc++)
        #pragma unroll
        for (int g = 0; g < 4; g++) ufs[kc][g] = ldB(3, kc, g);

    {   // step2: m-t2 = zxm[1] + hbM[1]@Um
        f32x4 acc[4];
        #pragma unroll
        for (int g = 0; g < 4; g++) acc[g] = zxm[1][g];
        #pragma unroll
        for (int kc = 0; kc < 4; kc++) {
            s16x8 a = load_afrag(&hbM[1][0][0], kc);
            #pragma unroll
            for (int g = 0; g < 4; g++)
                acc[g] = __builtin_amdgcn_mfma_f32_16x16x32_bf16(a, ufm[kc][g], acc[g], 0, 0, 0);
        }
        gates(acc, bzm, ccm, 0, 0);                    // write hbM[0]
    }
    __syncthreads();                                   // S2

    {   // step3: m-t3 (zxm[2] + hbM[0]@Um)  ||  s-t1 (zxs1 + hbS[0]@Us) — 2x MFMA ILP
        f32x4 am[4], as_[4];
        #pragma unroll
        for (int g = 0; g < 4; g++) { am[g] = zxm[2][g]; as_[g] = zxs1[g]; }
        #pragma unroll
        for (int kc = 0; kc < 4; kc++) {
            s16x8 aM = load_afrag(&hbM[0][0][0], kc);
            s16x8 aS = load_afrag(&hbS[0][0][0], kc);
            #pragma unroll
            for (int g = 0; g < 4; g++) {
                am[g]  = __builtin_amdgcn_mfma_f32_16x16x32_bf16(aM, ufm[kc][g], am[g],  0, 0, 0);
                as_[g] = __builtin_amdgcn_mfma_f32_16x16x32_bf16(aS, ufs[kc][g], as_[g], 0, 0, 0);
            }
        }
        gates(am,  bzm, ccm, 0, 1);                    // write hbM[1]
        gates(as_, bzs, ccs, 3, 1);                    // write hbS[1]
    }
    __syncthreads();                                   // S3

    // ---- issue wfs2 stream now: latency hides under step4, consumed in step5 ----
    s16x8 wfs2[4][4];
    #pragma unroll
    for (int kc = 0; kc < 4; kc++)
        #pragma unroll
        for (int g = 0; g < 4; g++) wfs2[kc][g] = ldB(2, kc, g);

    {   // step4: m-t4 = zxm[3] + hbM[1]@Um -> h_m -> xs[0]
        f32x4 acc[4];
        #pragma unroll
        for (int g = 0; g < 4; g++) acc[g] = zxm[3][g];
        #pragma unroll
        for (int kc = 0; kc < 4; kc++) {
            s16x8 a = load_afrag(&hbM[1][0][0], kc);
            #pragma unroll
            for (int g = 0; g < 4; g++)
                acc[g] = __builtin_amdgcn_mfma_f32_16x16x32_bf16(a, ufm[kc][g], acc[g], 0, 0, 0);
        }
        gates(acc, bzm, ccm, 1, 0);                    // h_m -> xs[0]
    }
    __syncthreads();                                   // S4

    {   // step5: s-t2 = h_m@Ws + hbS[1]@Us -> fp32 layer output (+ bf16 mirror)
        f32x4 acc[4];
        #pragma unroll
        for (int g = 0; g < 4; g++) acc[g] = (f32x4){0.f, 0.f, 0.f, 0.f};
        #pragma unroll
        for (int kc = 0; kc < 4; kc++) {
            s16x8 a0 = load_afrag(&xs[0][0][0], kc);
            s16x8 aS = load_afrag(&hbS[1][0][0], kc);
            #pragma unroll
            for (int g = 0; g < 4; g++) {
                acc[g] = __builtin_amdgcn_mfma_f32_16x16x32_bf16(a0, wfs2[kc][g], acc[g], 0, 0, 0);
                acc[g] = __builtin_amdgcn_mfma_f32_16x16x32_bf16(aS, ufs[kc][g],  acc[g], 0, 0, 0);
            }
        }
        gates(acc, bzs, ccs, 2, 0);                    // emb out
    }
}

// ----------------------------- fallback (no workspace): proven per-layer kernel -----------------------------
__global__ __launch_bounds__(TPB, 1) void layer_kernel_direct(
    float* __restrict__ emb, const int* __restrict__ prop_ids, const int* __restrict__ super_ids,
    const float* __restrict__ Wm, const float* __restrict__ Um, const float* __restrict__ bm,
    const float* __restrict__ Ws, const float* __restrict__ Us, const float* __restrict__ bs,
    const float* __restrict__ empty, int l) {

    __shared__ __align__(16) u16  xs[6][CHUNK][XPAD];
    __shared__ __align__(16) u16  hbuf[2][CHUNK][XPAD];
    __shared__ __align__(16) u16  empty_s[XPAD];

    const int tid  = threadIdx.x;
    const int b    = blockIdx.x;
    const int g0   = b * CHUNK;
    const size_t row0 = (size_t)l * M_NODES + g0;

    const int wv   = tid >> 6;
    const int lane = tid & 63;
    const int q    = lane >> 4, nl = lane & 15;
    const int d    = wv * 16 + nl;

    if (tid < 384) {
        int quarter = tid & 3;
        int r    = tid >> 2;
        int slot = r >> 4;
        int node = r & 15;
        size_t idx;
        if (slot < 4) idx = (size_t)prop_ids [((size_t)l * M_NODES + g0 + node) * 4 + slot];
        else          idx = (size_t)super_ids[((size_t)l * M_NODES + g0 + node) * 2 + (slot - 4)];
        const float4* src = (const float4*)(emb + idx * DIM);
        u16* dst = &xs[slot][node][0];
        int e0 = quarter * 32;
        #pragma unroll
        for (int j = 0; j < 8; j++) {
            float4 v = src[(e0 >> 2) + j];
            int o = e0 + j * 4;
            dst[o] = f2bf(v.x); dst[o + 1] = f2bf(v.y);
            dst[o + 2] = f2bf(v.z); dst[o + 3] = f2bf(v.w);
        }
    } else if (tid < 384 + 128) {
        int dd = tid - 384;
        empty_s[dd] = f2bf(empty[dd]);
    }
    __syncthreads();

    auto load_bfrag_direct = [&](const float* B, int kc, int g) -> s16x8 {
        int kb = kc * 32 + q * 8;
        int n  = g * 128 + d;
        s16x8 f;
        #pragma unroll
        for (int j = 0; j < 8; j++) f[j] = (short)f2bf(B[(size_t)(kb + j) * FD + n]);
        return f;
    };
    auto load_afrag = [&](const u16* X, int kc) -> s16x8 {
        return *(const s16x8*)(X + (size_t)nl * XPAD + kc * 32 + q * 8);
    };

    auto run_phase = [&](const float* Wg, const float* Ug, const float* bias,
                         int nsteps, const int* slots, bool write_hm, bool write_out) {
        s16x8 wf[4][4], uf[4][4];
        #pragma unroll
        for (int kc = 0; kc < 4; kc++) {
            #pragma unroll
            for (int g = 0; g < 4; g++) {
                wf[kc][g] = load_bfrag_direct(Wg, kc, g);
                uf[kc][g] = load_bfrag_direct(Ug, kc, g);
            }
        }
        float bz[4];
        #pragma unroll
        for (int g = 0; g < 4; g++) bz[g] = bias[g * 128 + d];
        float cc[4] = {0.f, 0.f, 0.f, 0.f};

        #pragma unroll 1
        for (int t = 0; t < nsteps; t++) {
            int s = slots[t];
            f32x4 acc[4];
            #pragma unroll
            for (int g = 0; g < 4; g++) acc[g] = (f32x4){0.f, 0.f, 0.f, 0.f};
            #pragma unroll
            for (int kc = 0; kc < 4; kc++) {
                s16x8 a = (s < 0) ? *(const s16x8*)(&empty_s[kc * 32 + q * 8])
                                  : load_afrag(&xs[s][0][0], kc);
                #pragma unroll
                for (int g = 0; g < 4; g++)
                    acc[g] = __builtin_amdgcn_mfma_f32_16x16x32_bf16(a, wf[kc][g], acc[g], 0, 0, 0);
            }
            if (t > 0) {
                __syncthreads();
                const u16* hb = &hbuf[(t - 1) & 1][0][0];
                #pragma unroll
                for (int kc = 0; kc < 4; kc++) {
                    s16x8 a = load_afrag(hb, kc);
                    #pragma unroll
                    for (int g = 0; g < 4; g++)
                        acc[g] = __builtin_amdgcn_mfma_f32_16x16x32_bf16(a, uf[kc][g], acc[g], 0, 0, 0);
                }
            }
            bool last = (t == nsteps - 1);
            #pragma unroll
            for (int r2 = 0; r2 < 4; r2++) {
                int m = q * 4 + r2;
                float zi = acc[0][r2] + bz[0];
                float zf = acc[1][r2] + bz[1];
                float zg = acc[2][r2] + bz[2];
                float zo = acc[3][r2] + bz[3];
                float c  = sigm(zf) * cc[r2] + sigm(zi) * tanh_f(zg);
                cc[r2] = c;
                float h  = sigm(zo) * tanh_f(c);
                if (!last)          hbuf[t & 1][m][d] = f2bf(h);
                else if (write_hm)  xs[0][m][d] = f2bf(h);
                else if (write_out) emb[(row0 + m) * DIM + d] = h;
            }
        }
    };

    {
        const int slots_m[5] = {-1, 0, 1, 2, 3};
        run_phase(Wm, Um, bm, 5, slots_m, true, false);
    }
    {
        const int slots_s[3] = {4, 5, 0};
        run_phase(Ws, Us, bs, 3, slots_s, false, true);
    }
}

extern "C" void kernel_launch(void* const* d_in, const int* in_sizes, int n_in,
                              void* d_out, int out_size, void* d_ws, size_t ws_size,
                              hipStream_t stream) {
    const int*   names = (const int*)d_in[0];
    const int*   pids  = (const int*)d_in[1];
    const int*   sids  = (const int*)d_in[2];
    const float* table = (const float*)d_in[3];
    const float* Wm    = (const float*)d_in[4];
    const float* Um    = (const float*)d_in[5];
    const float* bm    = (const float*)d_in[6];
    const float* Ws    = (const float*)d_in[7];
    const float* Us    = (const float*)d_in[8];
    const float* bs    = (const float*)d_in[9];
    const float* empt  = (const float*)d_in[10];
    float* emb  = (float*)d_out;
    u16* packed = (u16*)d_ws;

    const size_t packed_bytes = (size_t)4 * 4 * 32 * 64 * 8 * sizeof(u16);  // 512 KB
    const size_t t0_bytes     = 640 * sizeof(float);
    const size_t mirror_off   = (size_t)1 << 20;                            // 1 MB
    const size_t mirror_bytes = (size_t)LAYERS * M_NODES * DIM * sizeof(u16); // 32 MB
    const bool ws_packed = ws_size >= packed_bytes + t0_bytes;
    const bool ws_mirror = ws_size >= mirror_off + mirror_bytes;

    if (ws_packed) {
        float* t0buf = (float*)((char*)d_ws + packed_bytes);
        u16*   emb16 = ws_mirror ? (u16*)((char*)d_ws + mirror_off) : (u16*)nullptr;
        if (ws_mirror) {
            setup_kernel<true><<<385, 256, 0, stream>>>(names, table, emb, Wm, Um, Ws, Us,
                                                        bm, empt, packed, t0buf, emb16);
            for (int l = 1; l < LAYERS; l++)
                layer5_kernel<true><<<NBLK, TPB, 0, stream>>>(emb, pids, sids, bm, bs,
                                                              packed, t0buf, emb16, l);
        } else {
            setup_kernel<false><<<385, 256, 0, stream>>>(names, table, emb, Wm, Um, Ws, Us,
                                                         bm, empt, packed, t0buf, emb16);
            for (int l = 1; l < LAYERS; l++)
                layer5_kernel<false><<<NBLK, TPB, 0, stream>>>(emb, pids, sids, bm, bs,
                                                               packed, t0buf, emb16, l);
        }
    } else {
        l0_kernel<<<256, 256, 0, stream>>>(names, table, emb);
        for (int l = 1; l < LAYERS; l++)
            layer_kernel_direct<<<NBLK, TPB, 0, stream>>>(emb, pids, sids, Wm, Um, bm,
                                                          Ws, Us, bs, empt, l);
    }
}